// Round 4
// baseline (174.826 us; speedup 1.0000x reference)
//
#include <hip/hip_runtime.h>
#include <stdint.h>

#define D_FEAT 128
#define ALPHA_ 0.1f
#define SCANB 1024
#define TILE 128
#define NMAX 10240   // LDS per-node arrays sized for N<=NMAX (40KB)

// ---------- no-atomic CSC path ----------

// Phase A1: per-chunk in-degree histogram via LDS atomics
__global__ void k_hist_chunk(const int* __restrict__ col, uint32_t* __restrict__ hist_b,
                             int E, int chunk, int N) {
    __shared__ uint32_t lh[NMAX];
    int b = blockIdx.x;
    for (int i = threadIdx.x; i < N; i += blockDim.x) lh[i] = 0;
    __syncthreads();
    int lo = b * chunk, hi = min(lo + chunk, E);
    for (int e = lo + threadIdx.x; e < hi; e += blockDim.x)
        atomicAdd(&lh[col[e]], 1u);
    __syncthreads();
    uint32_t* out = hist_b + (size_t)b * N;
    for (int i = threadIdx.x; i < N; i += blockDim.x) out[i] = lh[i];
}

// Phase A2: per-chunk weighted out-degree, fixed-point (exact integer adds)
__global__ void k_wsum_chunk(const int* __restrict__ row, const float* __restrict__ w,
                             uint32_t* __restrict__ wsfix_b, int E, int chunk, int N,
                             float scale) {
    __shared__ uint32_t lw[NMAX];
    int b = blockIdx.x;
    for (int i = threadIdx.x; i < N; i += blockDim.x) lw[i] = 0;
    __syncthreads();
    int lo = b * chunk, hi = min(lo + chunk, E);
    for (int e = lo + threadIdx.x; e < hi; e += blockDim.x) {
        uint32_t q = (uint32_t)(w[e] * scale + 0.5f);
        atomicAdd(&lw[row[e]], q);
    }
    __syncthreads();
    uint32_t* out = wsfix_b + (size_t)b * N;
    for (int i = threadIdx.x; i < N; i += blockDim.x) out[i] = lw[i];
}

// Phase B1: column-reduce the per-chunk partials -> hist[n], ws[n]
__global__ void k_reduce(const uint32_t* __restrict__ hist_b,
                         const uint32_t* __restrict__ wsfix_b,
                         int* __restrict__ hist, float* __restrict__ wsf,
                         int B, int N, double inv_scale) {
    int n = blockIdx.x * blockDim.x + threadIdx.x;
    if (n >= N) return;
    uint32_t h = 0; uint64_t wq = 0;
    for (int b = 0; b < B; b++) {
        h  += hist_b [(size_t)b * N + n];
        wq += wsfix_b[(size_t)b * N + n];
    }
    hist[n] = (int)h;
    wsf[n] = (float)((double)wq * inv_scale);
}

// Phase B2: single-block exclusive scan of hist -> start[0..N] (cursor optional)
__global__ void k_scan(const int* __restrict__ hist, int* __restrict__ start,
                       int* __restrict__ cursor, int N) {
    __shared__ int lds[SCANB];
    int t = threadIdx.x;
    int CH = (N + SCANB - 1) / SCANB;
    int lo = t * CH, hi = min(lo + CH, N);
    int s = 0;
    for (int i = lo; i < hi; i++) s += hist[i];
    lds[t] = s;
    __syncthreads();
    for (int off = 1; off < SCANB; off <<= 1) {
        int v = (t >= off) ? lds[t - off] : 0;
        __syncthreads();
        lds[t] += v;
        __syncthreads();
    }
    int run = lds[t] - s;
    for (int i = lo; i < hi; i++) {
        start[i] = run;
        if (cursor) cursor[i] = run;
        run += hist[i];
    }
    if (t == SCANB - 1) start[N] = run;
}

// Phase B3: convert per-chunk histograms (in place) to per-chunk base offsets
__global__ void k_offsets(uint32_t* __restrict__ hist_b, const int* __restrict__ start,
                          int B, int N) {
    int n = blockIdx.x * blockDim.x + threadIdx.x;
    if (n >= N) return;
    uint32_t run = (uint32_t)start[n];
    for (int b = 0; b < B; b++) {
        size_t idx = (size_t)b * N + n;
        uint32_t h = hist_b[idx];
        hist_b[idx] = run;
        run += h;
    }
}

// Phase C: scatter records using LDS cursors (zero global atomics)
__global__ void k_build_chunk(const int* __restrict__ row, const int* __restrict__ col,
                              const float* __restrict__ w, const float* __restrict__ wsf,
                              const uint32_t* __restrict__ off_b, int2* __restrict__ rec,
                              int E, int chunk, int N) {
    __shared__ uint32_t cur[NMAX];
    int b = blockIdx.x;
    const uint32_t* off = off_b + (size_t)b * N;
    for (int i = threadIdx.x; i < N; i += blockDim.x) cur[i] = off[i];
    __syncthreads();
    int lo = b * chunk, hi = min(lo + chunk, E);
    for (int e = lo + threadIdx.x; e < hi; e += blockDim.x) {
        int c = col[e], r = row[e];
        float norm = (1.0f - ALPHA_) * w[e] / fmaxf(wsf[r], 1.0f);
        uint32_t pos = atomicAdd(&cur[c], 1u);
        rec[pos] = make_int2(r, __float_as_int(norm));
    }
}

// Gather: one block per destination node, one thread per feature; atomic-free
__global__ void k_gather(const int* __restrict__ start, const int2* __restrict__ rec,
                         const float* __restrict__ x, float* __restrict__ out, int N) {
    int c = blockIdx.x;
    int f = threadIdx.x;
    int s = start[c], e = start[c + 1];
    float acc = ALPHA_ * x[(size_t)c * D_FEAT + f];
    __shared__ int2 lds[TILE];
    for (int base = s; base < e; base += TILE) {
        int n = min(TILE, e - base);
        if (f < n) lds[f] = rec[base + f];
        __syncthreads();
        #pragma unroll 4
        for (int i = 0; i < n; i++) {
            int2 rc = lds[i];
            acc += __int_as_float(rc.y) * x[(size_t)rc.x * D_FEAT + f];
        }
        __syncthreads();
    }
    out[(size_t)c * D_FEAT + f] = acc;
}

// ---------- fallback: R1 global-atomic CSC build (needs only ~5.4MB ws) ----------

__global__ void k_edge_pass1(const int* __restrict__ row, const int* __restrict__ col,
                             const float* __restrict__ w,
                             float* __restrict__ ws, int* __restrict__ hist, int E) {
    int e = blockIdx.x * blockDim.x + threadIdx.x;
    if (e < E) {
        atomicAdd(&ws[row[e]], w[e]);
        atomicAdd(&hist[col[e]], 1);
    }
}

__global__ void k_build(const int* __restrict__ row, const int* __restrict__ col,
                        const float* __restrict__ w, const float* __restrict__ ws,
                        int* __restrict__ cursor, int2* __restrict__ rec, int E) {
    int e = blockIdx.x * blockDim.x + threadIdx.x;
    if (e < E) {
        int c = col[e], r = row[e];
        float norm = (1.0f - ALPHA_) * w[e] / fmaxf(ws[r], 1.0f);
        int pos = atomicAdd(&cursor[c], 1);
        rec[pos] = make_int2(r, __float_as_int(norm));
    }
}

extern "C" void kernel_launch(void* const* d_in, const int* in_sizes, int n_in,
                              void* d_out, int out_size, void* d_ws, size_t ws_size,
                              hipStream_t stream) {
    const float* x  = (const float*)d_in[0];
    const int*   ei = (const int*)d_in[1];
    const float* ew = (const float*)d_in[2];
    int E = in_sizes[2];
    int N = in_sizes[0] / D_FEAT;
    const int* row = ei;
    const int* col = ei + E;
    float* out = (float*)d_out;

    // common small arrays
    float* wsf    = (float*)d_ws;                 // N
    int*   hist   = (int*)(wsf + N);              // N
    int*   startp = hist + N;                     // N+1
    int*   cursor = startp + N + 1;               // N (fallback only)
    uintptr_t aux_addr = ((uintptr_t)(cursor + N) + 15) & ~(uintptr_t)15;

    // choose chunk count B for the no-atomic path
    int Bn = 0; uintptr_t rec_addr = 0;
    if (N <= NMAX) {
        const int cands[3] = {256, 128, 64};
        for (int ci = 0; ci < 3; ci++) {
            int Bc = cands[ci];
            uintptr_t ra = aux_addr + (uintptr_t)2 * Bc * N * sizeof(uint32_t);
            ra = (ra + 15) & ~(uintptr_t)15;
            size_t need = (ra - (uintptr_t)d_ws) + (size_t)E * sizeof(int2);
            if (need <= ws_size) { Bn = Bc; rec_addr = ra; break; }
        }
    }

    if (Bn > 0) {
        uint32_t* hist_b  = (uint32_t*)aux_addr;
        uint32_t* wsfix_b = hist_b + (size_t)Bn * N;
        int2*     rec     = (int2*)rec_addr;
        int chunk = (E + Bn - 1) / Bn;
        // largest power-of-2 scale with chunk*scale < 2^32 (overflow-proof)
        int sh = 0;
        while (((uint64_t)chunk << (sh + 1)) < (1ull << 32)) sh++;
        float scale = (float)(1u << sh);
        double inv_scale = 1.0 / (double)(1u << sh);

        k_hist_chunk<<<Bn, 512, 0, stream>>>(col, hist_b, E, chunk, N);
        k_wsum_chunk<<<Bn, 512, 0, stream>>>(row, ew, wsfix_b, E, chunk, N, scale);
        k_reduce<<<(N + 255) / 256, 256, 0, stream>>>(hist_b, wsfix_b, hist, wsf, Bn, N, inv_scale);
        k_scan<<<1, SCANB, 0, stream>>>(hist, startp, (int*)nullptr, N);
        k_offsets<<<(N + 255) / 256, 256, 0, stream>>>(hist_b, startp, Bn, N);
        k_build_chunk<<<Bn, 512, 0, stream>>>(row, col, ew, wsf, hist_b, rec, E, chunk, N);
        k_gather<<<N, D_FEAT, 0, stream>>>(startp, rec, x, out, N);
    } else {
        // fallback: R1 global-atomic CSC build
        int2* rec = (int2*)aux_addr;
        hipMemsetAsync(d_ws, 0, (size_t)2 * N * sizeof(int), stream);
        int eb = (E + 255) / 256;
        k_edge_pass1<<<eb, 256, 0, stream>>>(row, col, ew, wsf, hist, E);
        k_scan<<<1, SCANB, 0, stream>>>(hist, startp, cursor, N);
        k_build<<<eb, 256, 0, stream>>>(row, col, ew, wsf, cursor, rec, E);
        k_gather<<<N, D_FEAT, 0, stream>>>(startp, rec, x, out, N);
    }
}

// Round 7
// 93.503 us; speedup vs baseline: 1.8697x; 1.8697x over previous
//
#include <hip/hip_runtime.h>
#include <stdint.h>

#define D_FEAT 128
#define ALPHA_ 0.1f
#define SCANB 1024
#define TILE 128
#define NMAX 10240   // LDS per-node arrays sized for N<=NMAX (40KB)
#define RSPLIT 16    // threads per node in reduce/offsets kernels

// ---------- no-atomic CSC path ----------

// Phase A1: per-chunk in-degree histogram via LDS atomics
__global__ void k_hist_chunk(const int* __restrict__ col, uint32_t* __restrict__ hist_b,
                             int E, int chunk, int N) {
    __shared__ uint32_t lh[NMAX];
    int b = blockIdx.x;
    for (int i = threadIdx.x; i < N; i += blockDim.x) lh[i] = 0;
    __syncthreads();
    int lo = b * chunk, hi = min(lo + chunk, E);
    for (int e = lo + threadIdx.x; e < hi; e += blockDim.x)
        atomicAdd(&lh[col[e]], 1u);
    __syncthreads();
    uint32_t* out = hist_b + (size_t)b * N;
    for (int i = threadIdx.x; i < N; i += blockDim.x) out[i] = lh[i];
}

// Phase A2: per-chunk weighted out-degree, fixed-point (exact integer adds)
__global__ void k_wsum_chunk(const int* __restrict__ row, const float* __restrict__ w,
                             uint32_t* __restrict__ wsfix_b, int E, int chunk, int N,
                             float scale) {
    __shared__ uint32_t lw[NMAX];
    int b = blockIdx.x;
    for (int i = threadIdx.x; i < N; i += blockDim.x) lw[i] = 0;
    __syncthreads();
    int lo = b * chunk, hi = min(lo + chunk, E);
    for (int e = lo + threadIdx.x; e < hi; e += blockDim.x) {
        uint32_t q = (uint32_t)(w[e] * scale + 0.5f);
        atomicAdd(&lw[row[e]], q);
    }
    __syncthreads();
    uint32_t* out = wsfix_b + (size_t)b * N;
    for (int i = threadIdx.x; i < N; i += blockDim.x) out[i] = lw[i];
}

// Phase B1: column-reduce partials. 16 nodes x 16 segments per 256-thread block.
__global__ void k_reduce2(const uint32_t* __restrict__ hist_b,
                          const uint32_t* __restrict__ wsfix_b,
                          int* __restrict__ hist, float* __restrict__ wsf,
                          int B, int N, double inv_scale) {
    __shared__ uint32_t sh_h[16][RSPLIT];
    __shared__ uint64_t sh_w[16][RSPLIT];
    int nl = threadIdx.x & 15;
    int s  = threadIdx.x >> 4;
    int n  = blockIdx.x * 16 + nl;
    int per = B / RSPLIT;
    uint32_t h = 0; uint64_t wq = 0;
    if (n < N) {
        for (int i = 0; i < per; i++) {
            int b = s * per + i;
            h  += hist_b [(size_t)b * N + n];
            wq += wsfix_b[(size_t)b * N + n];
        }
    }
    sh_h[nl][s] = h; sh_w[nl][s] = wq;
    __syncthreads();
    if (s == 0 && n < N) {
        uint32_t H = 0; uint64_t W = 0;
        #pragma unroll
        for (int i = 0; i < RSPLIT; i++) { H += sh_h[nl][i]; W += sh_w[nl][i]; }
        hist[n] = (int)H;
        wsf[n] = (float)((double)W * inv_scale);
    }
}

// Phase B2: single-block exclusive scan of hist -> start[0..N]
__global__ void k_scan(const int* __restrict__ hist, int* __restrict__ start,
                       int* __restrict__ cursor, int N) {
    __shared__ int lds[SCANB];
    int t = threadIdx.x;
    int CH = (N + SCANB - 1) / SCANB;
    int lo = t * CH, hi = min(lo + CH, N);
    int s = 0;
    for (int i = lo; i < hi; i++) s += hist[i];
    lds[t] = s;
    __syncthreads();
    for (int off = 1; off < SCANB; off <<= 1) {
        int v = (t >= off) ? lds[t - off] : 0;
        __syncthreads();
        lds[t] += v;
        __syncthreads();
    }
    int run = lds[t] - s;
    for (int i = lo; i < hi; i++) {
        start[i] = run;
        if (cursor) cursor[i] = run;
        run += hist[i];
    }
    if (t == SCANB - 1) start[N] = run;
}

// Phase B3: per-chunk histograms -> per-chunk base offsets (parallel over segments)
__global__ void k_offsets2(uint32_t* __restrict__ hist_b, const int* __restrict__ start,
                           int B, int N) {
    __shared__ uint32_t sh[16][RSPLIT];
    int nl = threadIdx.x & 15;
    int s  = threadIdx.x >> 4;
    int n  = blockIdx.x * 16 + nl;
    int per = B / RSPLIT;
    uint32_t vals[16];
    uint32_t sum = 0;
    if (n < N) {
        for (int i = 0; i < per; i++) {
            vals[i] = hist_b[(size_t)(s * per + i) * N + n];
            sum += vals[i];
        }
    }
    sh[nl][s] = sum;
    __syncthreads();
    uint32_t pre = 0;
    for (int i = 0; i < s; i++) pre += sh[nl][i];
    if (n < N) {
        uint32_t run = (uint32_t)start[n] + pre;
        for (int i = 0; i < per; i++) {
            uint32_t h = vals[i];
            hist_b[(size_t)(s * per + i) * N + n] = run;
            run += h;
        }
    }
}

// Phase C: scatter records using LDS cursors (zero global atomics)
__global__ void k_build_chunk(const int* __restrict__ row, const int* __restrict__ col,
                              const float* __restrict__ w, const float* __restrict__ wsf,
                              const uint32_t* __restrict__ off_b, int2* __restrict__ rec,
                              int E, int chunk, int N) {
    __shared__ uint32_t cur[NMAX];
    int b = blockIdx.x;
    const uint32_t* off = off_b + (size_t)b * N;
    for (int i = threadIdx.x; i < N; i += blockDim.x) cur[i] = off[i];
    __syncthreads();
    int lo = b * chunk, hi = min(lo + chunk, E);
    for (int e = lo + threadIdx.x; e < hi; e += blockDim.x) {
        int c = col[e], r = row[e];
        float norm = (1.0f - ALPHA_) * w[e] / fmaxf(wsf[r], 1.0f);
        uint32_t pos = atomicAdd(&cur[c], 1u);
        rec[pos] = make_int2(r, __float_as_int(norm));
    }
}

// Gather: one 64-thread wave per destination node, float2 per lane; atomic-free
__global__ void k_gather(const int* __restrict__ start, const int2* __restrict__ rec,
                         const float* __restrict__ x, float* __restrict__ out, int N) {
    int c = blockIdx.x;
    int f = threadIdx.x;             // 0..63
    int s = start[c], e = start[c + 1];
    const float2* x2 = (const float2*)x;
    float2 acc = x2[(size_t)c * (D_FEAT / 2) + f];
    acc.x *= ALPHA_; acc.y *= ALPHA_;
    __shared__ int2 lds[TILE];
    for (int base = s; base < e; base += TILE) {
        int n = min(TILE, e - base);
        for (int i = f; i < n; i += 64) lds[i] = rec[base + i];
        __syncthreads();
        #pragma unroll 4
        for (int i = 0; i < n; i++) {
            int2 rc = lds[i];
            float nw = __int_as_float(rc.y);
            float2 v = x2[(size_t)rc.x * (D_FEAT / 2) + f];
            acc.x += nw * v.x;
            acc.y += nw * v.y;
        }
        __syncthreads();
    }
    ((float2*)out)[(size_t)c * (D_FEAT / 2) + f] = acc;
}

// ---------- fallback: global-atomic CSC build (needs only ~5.4MB ws) ----------

__global__ void k_edge_pass1(const int* __restrict__ row, const int* __restrict__ col,
                             const float* __restrict__ w,
                             float* __restrict__ ws, int* __restrict__ hist, int E) {
    int e = blockIdx.x * blockDim.x + threadIdx.x;
    if (e < E) {
        atomicAdd(&ws[row[e]], w[e]);
        atomicAdd(&hist[col[e]], 1);
    }
}

__global__ void k_build(const int* __restrict__ row, const int* __restrict__ col,
                        const float* __restrict__ w, const float* __restrict__ ws,
                        int* __restrict__ cursor, int2* __restrict__ rec, int E) {
    int e = blockIdx.x * blockDim.x + threadIdx.x;
    if (e < E) {
        int c = col[e], r = row[e];
        float norm = (1.0f - ALPHA_) * w[e] / fmaxf(ws[r], 1.0f);
        int pos = atomicAdd(&cursor[c], 1);
        rec[pos] = make_int2(r, __float_as_int(norm));
    }
}

extern "C" void kernel_launch(void* const* d_in, const int* in_sizes, int n_in,
                              void* d_out, int out_size, void* d_ws, size_t ws_size,
                              hipStream_t stream) {
    const float* x  = (const float*)d_in[0];
    const int*   ei = (const int*)d_in[1];
    const float* ew = (const float*)d_in[2];
    int E = in_sizes[2];
    int N = in_sizes[0] / D_FEAT;
    const int* row = ei;
    const int* col = ei + E;
    float* out = (float*)d_out;

    // common small arrays
    float* wsf    = (float*)d_ws;                 // N
    int*   hist   = (int*)(wsf + N);              // N
    int*   startp = hist + N;                     // N+1
    int*   cursor = startp + N + 1;               // N (fallback only)
    uintptr_t aux_addr = ((uintptr_t)(cursor + N) + 15) & ~(uintptr_t)15;

    // choose chunk count B for the no-atomic path
    int Bn = 0; uintptr_t rec_addr = 0;
    if (N <= NMAX) {
        const int cands[3] = {256, 128, 64};
        for (int ci = 0; ci < 3; ci++) {
            int Bc = cands[ci];
            uintptr_t ra = aux_addr + (uintptr_t)2 * Bc * N * sizeof(uint32_t);
            ra = (ra + 15) & ~(uintptr_t)15;
            size_t need = (ra - (uintptr_t)d_ws) + (size_t)E * sizeof(int2);
            if (need <= ws_size) { Bn = Bc; rec_addr = ra; break; }
        }
    }

    if (Bn > 0) {
        uint32_t* hist_b  = (uint32_t*)aux_addr;
        uint32_t* wsfix_b = hist_b + (size_t)Bn * N;
        int2*     rec     = (int2*)rec_addr;
        int chunk = (E + Bn - 1) / Bn;
        // largest power-of-2 scale with chunk*scale < 2^32 (overflow-proof)
        int sh = 0;
        while (((uint64_t)chunk << (sh + 1)) < (1ull << 32)) sh++;
        float scale = (float)(1u << sh);
        double inv_scale = 1.0 / (double)(1u << sh);
        int nb16 = (N + 15) / 16;   // blocks of 16 nodes for reduce/offsets

        k_hist_chunk<<<Bn, 512, 0, stream>>>(col, hist_b, E, chunk, N);
        k_wsum_chunk<<<Bn, 512, 0, stream>>>(row, ew, wsfix_b, E, chunk, N, scale);
        k_reduce2<<<nb16, 256, 0, stream>>>(hist_b, wsfix_b, hist, wsf, Bn, N, inv_scale);
        k_scan<<<1, SCANB, 0, stream>>>(hist, startp, (int*)nullptr, N);
        k_offsets2<<<nb16, 256, 0, stream>>>(hist_b, startp, Bn, N);
        k_build_chunk<<<Bn, 512, 0, stream>>>(row, col, ew, wsf, hist_b, rec, E, chunk, N);
        k_gather<<<N, 64, 0, stream>>>(startp, rec, x, out, N);
    } else {
        // fallback: global-atomic CSC build
        int2* rec = (int2*)aux_addr;
        hipMemsetAsync(d_ws, 0, (size_t)2 * N * sizeof(int), stream);
        int eb = (E + 255) / 256;
        k_edge_pass1<<<eb, 256, 0, stream>>>(row, col, ew, wsf, hist, E);
        k_scan<<<1, SCANB, 0, stream>>>(hist, startp, cursor, N);
        k_build<<<eb, 256, 0, stream>>>(row, col, ew, wsf, cursor, rec, E);
        k_gather<<<N, 64, 0, stream>>>(startp, rec, x, out, N);
    }
}

// Round 8
// 88.275 us; speedup vs baseline: 1.9805x; 1.0592x over previous
//
#include <hip/hip_runtime.h>
#include <stdint.h>

#define D_FEAT 128
#define ALPHA_ 0.1f
#define SCANB 1024
#define TILE 128
#define NMAX 10240   // LDS per-node arrays sized for N<=NMAX (40KB each)
#define RSPLIT 16    // threads per node in reduce/offsets kernels

// ---------- no-atomic CSC path ----------

// Phase A (fused): per-chunk in-degree histogram + fixed-point weighted out-degree
__global__ void k_pass1(const int* __restrict__ row, const int* __restrict__ col,
                        const float* __restrict__ w,
                        uint32_t* __restrict__ hist_b, uint32_t* __restrict__ wsfix_b,
                        int E, int chunk, int N, float scale) {
    __shared__ uint32_t lh[NMAX];   // in-degree counts (by col)
    __shared__ uint32_t lw[NMAX];   // fixed-point weight sums (by row)
    int b = blockIdx.x;
    for (int i = threadIdx.x; i < N; i += blockDim.x) { lh[i] = 0; lw[i] = 0; }
    __syncthreads();
    int lo = b * chunk, hi = min(lo + chunk, E);
    for (int e = lo + threadIdx.x; e < hi; e += blockDim.x) {
        atomicAdd(&lh[col[e]], 1u);
        uint32_t q = (uint32_t)(w[e] * scale + 0.5f);
        atomicAdd(&lw[row[e]], q);
    }
    __syncthreads();
    uint32_t* oh = hist_b  + (size_t)b * N;
    uint32_t* ow = wsfix_b + (size_t)b * N;
    for (int i = threadIdx.x; i < N; i += blockDim.x) { oh[i] = lh[i]; ow[i] = lw[i]; }
}

// Phase B1: column-reduce partials. 16 nodes x 16 segments per 256-thread block.
__global__ void k_reduce2(const uint32_t* __restrict__ hist_b,
                          const uint32_t* __restrict__ wsfix_b,
                          int* __restrict__ hist, float* __restrict__ wsf,
                          int B, int N, double inv_scale) {
    __shared__ uint32_t sh_h[16][RSPLIT];
    __shared__ uint64_t sh_w[16][RSPLIT];
    int nl = threadIdx.x & 15;
    int s  = threadIdx.x >> 4;
    int n  = blockIdx.x * 16 + nl;
    int per = B / RSPLIT;
    uint32_t h = 0; uint64_t wq = 0;
    if (n < N) {
        for (int i = 0; i < per; i++) {
            int b = s * per + i;
            h  += hist_b [(size_t)b * N + n];
            wq += wsfix_b[(size_t)b * N + n];
        }
    }
    sh_h[nl][s] = h; sh_w[nl][s] = wq;
    __syncthreads();
    if (s == 0 && n < N) {
        uint32_t H = 0; uint64_t W = 0;
        #pragma unroll
        for (int i = 0; i < RSPLIT; i++) { H += sh_h[nl][i]; W += sh_w[nl][i]; }
        hist[n] = (int)H;
        wsf[n] = (float)((double)W * inv_scale);
    }
}

// Phase B2: single-block exclusive scan of hist -> start[0..N]
__global__ void k_scan(const int* __restrict__ hist, int* __restrict__ start,
                       int* __restrict__ cursor, int N) {
    __shared__ int lds[SCANB];
    int t = threadIdx.x;
    int CH = (N + SCANB - 1) / SCANB;
    int lo = t * CH, hi = min(lo + CH, N);
    int s = 0;
    for (int i = lo; i < hi; i++) s += hist[i];
    lds[t] = s;
    __syncthreads();
    for (int off = 1; off < SCANB; off <<= 1) {
        int v = (t >= off) ? lds[t - off] : 0;
        __syncthreads();
        lds[t] += v;
        __syncthreads();
    }
    int run = lds[t] - s;
    for (int i = lo; i < hi; i++) {
        start[i] = run;
        if (cursor) cursor[i] = run;
        run += hist[i];
    }
    if (t == SCANB - 1) start[N] = run;
}

// Phase B3: per-chunk histograms -> per-chunk base offsets (parallel over segments)
__global__ void k_offsets2(uint32_t* __restrict__ hist_b, const int* __restrict__ start,
                           int B, int N) {
    __shared__ uint32_t sh[16][RSPLIT];
    int nl = threadIdx.x & 15;
    int s  = threadIdx.x >> 4;
    int n  = blockIdx.x * 16 + nl;
    int per = B / RSPLIT;
    uint32_t vals[16];
    uint32_t sum = 0;
    if (n < N) {
        for (int i = 0; i < per; i++) {
            vals[i] = hist_b[(size_t)(s * per + i) * N + n];
            sum += vals[i];
        }
    }
    sh[nl][s] = sum;
    __syncthreads();
    uint32_t pre = 0;
    for (int i = 0; i < s; i++) pre += sh[nl][i];
    if (n < N) {
        uint32_t run = (uint32_t)start[n] + pre;
        for (int i = 0; i < per; i++) {
            uint32_t h = vals[i];
            hist_b[(size_t)(s * per + i) * N + n] = run;
            run += h;
        }
    }
}

// Phase C: scatter records using LDS cursors (zero global atomics)
__global__ void k_build_chunk(const int* __restrict__ row, const int* __restrict__ col,
                              const float* __restrict__ w, const float* __restrict__ wsf,
                              const uint32_t* __restrict__ off_b, int2* __restrict__ rec,
                              int E, int chunk, int N) {
    __shared__ uint32_t cur[NMAX];
    int b = blockIdx.x;
    const uint32_t* off = off_b + (size_t)b * N;
    for (int i = threadIdx.x; i < N; i += blockDim.x) cur[i] = off[i];
    __syncthreads();
    int lo = b * chunk, hi = min(lo + chunk, E);
    for (int e = lo + threadIdx.x; e < hi; e += blockDim.x) {
        int c = col[e], r = row[e];
        float norm = (1.0f - ALPHA_) * w[e] / fmaxf(wsf[r], 1.0f);
        uint32_t pos = atomicAdd(&cur[c], 1u);
        rec[pos] = make_int2(r, __float_as_int(norm));
    }
}

// Gather: one wave per destination node. Lanes 0-31 handle edge k, lanes 32-63
// edge k+1; each lane loads float4 (16B) of the row. Cross-half combine at end.
__global__ void k_gather(const int* __restrict__ start, const int2* __restrict__ rec,
                         const float* __restrict__ x, float* __restrict__ out, int N) {
    int c = blockIdx.x;
    int t = threadIdx.x;          // 0..63
    int half = t >> 5;            // 0 or 1
    int fl = t & 31;              // float4 slot within row (32 x 16B = 512B)
    int s = start[c], e = start[c + 1];
    const float4* x4 = (const float4*)x;
    float4 acc = make_float4(0.f, 0.f, 0.f, 0.f);
    __shared__ int2 lds[TILE];
    for (int base = s; base < e; base += TILE) {
        int n = min(TILE, e - base);
        for (int i = t; i < n; i += 64) lds[i] = rec[base + i];
        __syncthreads();
        #pragma unroll 2
        for (int k = 0; k < n; k += 2) {
            int idx = k + half;
            float nw = 0.f; int r = 0;
            if (idx < n) { int2 rc = lds[idx]; r = rc.x; nw = __int_as_float(rc.y); }
            float4 v = x4[(size_t)r * 32 + fl];
            acc.x += nw * v.x; acc.y += nw * v.y;
            acc.z += nw * v.z; acc.w += nw * v.w;
        }
        __syncthreads();
    }
    // combine the two half-wave accumulators
    acc.x += __shfl_xor(acc.x, 32, 64);
    acc.y += __shfl_xor(acc.y, 32, 64);
    acc.z += __shfl_xor(acc.z, 32, 64);
    acc.w += __shfl_xor(acc.w, 32, 64);
    if (half == 0) {
        float4 xc = x4[(size_t)c * 32 + fl];
        acc.x += ALPHA_ * xc.x; acc.y += ALPHA_ * xc.y;
        acc.z += ALPHA_ * xc.z; acc.w += ALPHA_ * xc.w;
        ((float4*)out)[(size_t)c * 32 + fl] = acc;
    }
}

// ---------- fallback: global-atomic CSC build (needs only ~5.4MB ws) ----------

__global__ void k_edge_pass1(const int* __restrict__ row, const int* __restrict__ col,
                             const float* __restrict__ w,
                             float* __restrict__ ws, int* __restrict__ hist, int E) {
    int e = blockIdx.x * blockDim.x + threadIdx.x;
    if (e < E) {
        atomicAdd(&ws[row[e]], w[e]);
        atomicAdd(&hist[col[e]], 1);
    }
}

__global__ void k_build(const int* __restrict__ row, const int* __restrict__ col,
                        const float* __restrict__ w, const float* __restrict__ ws,
                        int* __restrict__ cursor, int2* __restrict__ rec, int E) {
    int e = blockIdx.x * blockDim.x + threadIdx.x;
    if (e < E) {
        int c = col[e], r = row[e];
        float norm = (1.0f - ALPHA_) * w[e] / fmaxf(ws[r], 1.0f);
        int pos = atomicAdd(&cursor[c], 1);
        rec[pos] = make_int2(r, __float_as_int(norm));
    }
}

extern "C" void kernel_launch(void* const* d_in, const int* in_sizes, int n_in,
                              void* d_out, int out_size, void* d_ws, size_t ws_size,
                              hipStream_t stream) {
    const float* x  = (const float*)d_in[0];
    const int*   ei = (const int*)d_in[1];
    const float* ew = (const float*)d_in[2];
    int E = in_sizes[2];
    int N = in_sizes[0] / D_FEAT;
    const int* row = ei;
    const int* col = ei + E;
    float* out = (float*)d_out;

    // common small arrays
    float* wsf    = (float*)d_ws;                 // N
    int*   hist   = (int*)(wsf + N);              // N
    int*   startp = hist + N;                     // N+1
    int*   cursor = startp + N + 1;               // N (fallback only)
    uintptr_t aux_addr = ((uintptr_t)(cursor + N) + 15) & ~(uintptr_t)15;

    // choose chunk count B for the no-atomic path
    int Bn = 0; uintptr_t rec_addr = 0;
    if (N <= NMAX) {
        const int cands[3] = {256, 128, 64};
        for (int ci = 0; ci < 3; ci++) {
            int Bc = cands[ci];
            uintptr_t ra = aux_addr + (uintptr_t)2 * Bc * N * sizeof(uint32_t);
            ra = (ra + 15) & ~(uintptr_t)15;
            size_t need = (ra - (uintptr_t)d_ws) + (size_t)E * sizeof(int2);
            if (need <= ws_size) { Bn = Bc; rec_addr = ra; break; }
        }
    }

    if (Bn > 0) {
        uint32_t* hist_b  = (uint32_t*)aux_addr;
        uint32_t* wsfix_b = hist_b + (size_t)Bn * N;
        int2*     rec     = (int2*)rec_addr;
        int chunk = (E + Bn - 1) / Bn;
        // largest power-of-2 scale with chunk*scale < 2^32 (overflow-proof)
        int sh = 0;
        while (((uint64_t)chunk << (sh + 1)) < (1ull << 32)) sh++;
        float scale = (float)(1u << sh);
        double inv_scale = 1.0 / (double)(1u << sh);
        int nb16 = (N + 15) / 16;   // blocks of 16 nodes for reduce/offsets

        // no memset needed: every ws region below is fully overwritten before use
        k_pass1<<<Bn, 512, 0, stream>>>(row, col, ew, hist_b, wsfix_b, E, chunk, N, scale);
        k_reduce2<<<nb16, 256, 0, stream>>>(hist_b, wsfix_b, hist, wsf, Bn, N, inv_scale);
        k_scan<<<1, SCANB, 0, stream>>>(hist, startp, (int*)nullptr, N);
        k_offsets2<<<nb16, 256, 0, stream>>>(hist_b, startp, Bn, N);
        k_build_chunk<<<Bn, 512, 0, stream>>>(row, col, ew, wsf, hist_b, rec, E, chunk, N);
        k_gather<<<N, 64, 0, stream>>>(startp, rec, x, out, N);
    } else {
        // fallback: global-atomic CSC build
        int2* rec = (int2*)aux_addr;
        hipMemsetAsync(d_ws, 0, (size_t)2 * N * sizeof(int), stream);
        int eb = (E + 255) / 256;
        k_edge_pass1<<<eb, 256, 0, stream>>>(row, col, ew, wsf, hist, E);
        k_scan<<<1, SCANB, 0, stream>>>(hist, startp, cursor, N);
        k_build<<<eb, 256, 0, stream>>>(row, col, ew, wsf, cursor, rec, E);
        k_gather<<<N, 64, 0, stream>>>(startp, rec, x, out, N);
    }
}

// Round 11
// 83.894 us; speedup vs baseline: 2.0839x; 1.0522x over previous
//
#include <hip/hip_runtime.h>
#include <stdint.h>

#define D_FEAT 128
#define ALPHA_ 0.1f
#define SCANB 1024
#define TILE 128
#define NMAX 10240   // LDS per-node arrays sized for N<=NMAX (40KB each)
#define RSPLIT 16    // threads per node in reduce/offsets kernels
#define QSCALE 262144.0f   // 2^18 fixed-point scale for packed norm

// rec packing: [row:14 | norm_q:18], norm in [0,0.9] => q < 2^18
__device__ __forceinline__ uint32_t pack_rec(int r, float norm) {
    uint32_t q = (uint32_t)(norm * QSCALE + 0.5f);
    return ((uint32_t)r << 18) | q;
}

// ---------- no-atomic CSC path ----------

// Phase A (fused): per-chunk in-degree histogram + fixed-point weighted out-degree
__global__ void k_pass1(const int* __restrict__ row, const int* __restrict__ col,
                        const float* __restrict__ w,
                        uint32_t* __restrict__ hist_b, uint32_t* __restrict__ wsfix_b,
                        int E, int chunk, int N, float scale) {
    __shared__ uint32_t lh[NMAX];   // in-degree counts (by col)
    __shared__ uint32_t lw[NMAX];   // fixed-point weight sums (by row)
    int b = blockIdx.x;
    for (int i = threadIdx.x; i < N; i += blockDim.x) { lh[i] = 0; lw[i] = 0; }
    __syncthreads();
    int lo = b * chunk, hi = min(lo + chunk, E);
    for (int e = lo + threadIdx.x; e < hi; e += blockDim.x) {
        atomicAdd(&lh[col[e]], 1u);
        uint32_t q = (uint32_t)(w[e] * scale + 0.5f);
        atomicAdd(&lw[row[e]], q);
    }
    __syncthreads();
    uint32_t* oh = hist_b  + (size_t)b * N;
    uint32_t* ow = wsfix_b + (size_t)b * N;
    for (int i = threadIdx.x; i < N; i += blockDim.x) { oh[i] = lh[i]; ow[i] = lw[i]; }
}

// Phase B1: column-reduce partials. 16 nodes x 16 segments per 256-thread block.
__global__ void k_reduce2(const uint32_t* __restrict__ hist_b,
                          const uint32_t* __restrict__ wsfix_b,
                          int* __restrict__ hist, float* __restrict__ wsf,
                          int B, int N, double inv_scale) {
    __shared__ uint32_t sh_h[16][RSPLIT];
    __shared__ uint64_t sh_w[16][RSPLIT];
    int nl = threadIdx.x & 15;
    int s  = threadIdx.x >> 4;
    int n  = blockIdx.x * 16 + nl;
    int per = B / RSPLIT;
    uint32_t h = 0; uint64_t wq = 0;
    if (n < N) {
        for (int i = 0; i < per; i++) {
            int b = s * per + i;
            h  += hist_b [(size_t)b * N + n];
            wq += wsfix_b[(size_t)b * N + n];
        }
    }
    sh_h[nl][s] = h; sh_w[nl][s] = wq;
    __syncthreads();
    if (s == 0 && n < N) {
        uint32_t H = 0; uint64_t W = 0;
        #pragma unroll
        for (int i = 0; i < RSPLIT; i++) { H += sh_h[nl][i]; W += sh_w[nl][i]; }
        hist[n] = (int)H;
        wsf[n] = (float)((double)W * inv_scale);
    }
}

// Phase B2: single-block exclusive scan of hist -> start[0..N]
__global__ void k_scan(const int* __restrict__ hist, int* __restrict__ start,
                       int* __restrict__ cursor, int N) {
    __shared__ int lds[SCANB];
    int t = threadIdx.x;
    int CH = (N + SCANB - 1) / SCANB;
    int lo = t * CH, hi = min(lo + CH, N);
    int s = 0;
    for (int i = lo; i < hi; i++) s += hist[i];
    lds[t] = s;
    __syncthreads();
    for (int off = 1; off < SCANB; off <<= 1) {
        int v = (t >= off) ? lds[t - off] : 0;
        __syncthreads();
        lds[t] += v;
        __syncthreads();
    }
    int run = lds[t] - s;
    for (int i = lo; i < hi; i++) {
        start[i] = run;
        if (cursor) cursor[i] = run;
        run += hist[i];
    }
    if (t == SCANB - 1) start[N] = run;
}

// Phase B3: per-chunk histograms -> per-chunk base offsets (parallel over segments)
__global__ void k_offsets2(uint32_t* __restrict__ hist_b, const int* __restrict__ start,
                           int B, int N) {
    __shared__ uint32_t sh[16][RSPLIT];
    int nl = threadIdx.x & 15;
    int s  = threadIdx.x >> 4;
    int n  = blockIdx.x * 16 + nl;
    int per = B / RSPLIT;
    uint32_t vals[16];
    uint32_t sum = 0;
    if (n < N) {
        for (int i = 0; i < per; i++) {
            vals[i] = hist_b[(size_t)(s * per + i) * N + n];
            sum += vals[i];
        }
    }
    sh[nl][s] = sum;
    __syncthreads();
    uint32_t pre = 0;
    for (int i = 0; i < s; i++) pre += sh[nl][i];
    if (n < N) {
        uint32_t run = (uint32_t)start[n] + pre;
        for (int i = 0; i < per; i++) {
            uint32_t h = vals[i];
            hist_b[(size_t)(s * per + i) * N + n] = run;
            run += h;
        }
    }
}

// Phase C: scatter packed records using LDS cursors (zero global atomics)
__global__ void k_build_chunk(const int* __restrict__ row, const int* __restrict__ col,
                              const float* __restrict__ w, const float* __restrict__ wsf,
                              const uint32_t* __restrict__ off_b, uint32_t* __restrict__ rec,
                              int E, int chunk, int N) {
    __shared__ uint32_t cur[NMAX];
    int b = blockIdx.x;
    const uint32_t* off = off_b + (size_t)b * N;
    for (int i = threadIdx.x; i < N; i += blockDim.x) cur[i] = off[i];
    __syncthreads();
    int lo = b * chunk, hi = min(lo + chunk, E);
    for (int e = lo + threadIdx.x; e < hi; e += blockDim.x) {
        int c = col[e], r = row[e];
        float norm = (1.0f - ALPHA_) * w[e] / fmaxf(wsf[r], 1.0f);
        uint32_t pos = atomicAdd(&cur[c], 1u);
        rec[pos] = pack_rec(r, norm);
    }
}

// Gather: one wave per destination node. Lanes 0-31 handle edge k, lanes 32-63
// edge k+1; each lane loads float4 (16B) of the row. Cross-half combine at end.
__global__ void k_gather(const int* __restrict__ start, const uint32_t* __restrict__ rec,
                         const float* __restrict__ x, float* __restrict__ out, int N) {
    int c = blockIdx.x;
    int t = threadIdx.x;          // 0..63
    int half = t >> 5;            // 0 or 1
    int fl = t & 31;              // float4 slot within row (32 x 16B = 512B)
    int s = start[c], e = start[c + 1];
    const float4* x4 = (const float4*)x;
    float4 acc = make_float4(0.f, 0.f, 0.f, 0.f);
    __shared__ uint32_t lds[TILE];
    for (int base = s; base < e; base += TILE) {
        int n = min(TILE, e - base);
        for (int i = t; i < n; i += 64) lds[i] = rec[base + i];
        __syncthreads();
        #pragma unroll 2
        for (int k = 0; k < n; k += 2) {
            int idx = k + half;
            float nw = 0.f; int r = 0;
            if (idx < n) {
                uint32_t p = lds[idx];
                r = (int)(p >> 18);
                nw = (float)(p & 0x3FFFFu) * (1.0f / QSCALE);
            }
            float4 v = x4[(size_t)r * 32 + fl];
            acc.x += nw * v.x; acc.y += nw * v.y;
            acc.z += nw * v.z; acc.w += nw * v.w;
        }
        __syncthreads();
    }
    // combine the two half-wave accumulators
    acc.x += __shfl_xor(acc.x, 32, 64);
    acc.y += __shfl_xor(acc.y, 32, 64);
    acc.z += __shfl_xor(acc.z, 32, 64);
    acc.w += __shfl_xor(acc.w, 32, 64);
    if (half == 0) {
        float4 xc = x4[(size_t)c * 32 + fl];
        acc.x += ALPHA_ * xc.x; acc.y += ALPHA_ * xc.y;
        acc.z += ALPHA_ * xc.z; acc.w += ALPHA_ * xc.w;
        ((float4*)out)[(size_t)c * 32 + fl] = acc;
    }
}

// ---------- fallback: global-atomic CSC build (needs only ~3MB ws) ----------

__global__ void k_edge_pass1(const int* __restrict__ row, const int* __restrict__ col,
                             const float* __restrict__ w,
                             float* __restrict__ ws, int* __restrict__ hist, int E) {
    int e = blockIdx.x * blockDim.x + threadIdx.x;
    if (e < E) {
        atomicAdd(&ws[row[e]], w[e]);
        atomicAdd(&hist[col[e]], 1);
    }
}

__global__ void k_build(const int* __restrict__ row, const int* __restrict__ col,
                        const float* __restrict__ w, const float* __restrict__ ws,
                        int* __restrict__ cursor, uint32_t* __restrict__ rec, int E) {
    int e = blockIdx.x * blockDim.x + threadIdx.x;
    if (e < E) {
        int c = col[e], r = row[e];
        float norm = (1.0f - ALPHA_) * w[e] / fmaxf(ws[r], 1.0f);
        int pos = atomicAdd(&cursor[c], 1);
        rec[pos] = pack_rec(r, norm);
    }
}

extern "C" void kernel_launch(void* const* d_in, const int* in_sizes, int n_in,
                              void* d_out, int out_size, void* d_ws, size_t ws_size,
                              hipStream_t stream) {
    const float* x  = (const float*)d_in[0];
    const int*   ei = (const int*)d_in[1];
    const float* ew = (const float*)d_in[2];
    int E = in_sizes[2];
    int N = in_sizes[0] / D_FEAT;
    const int* row = ei;
    const int* col = ei + E;
    float* out = (float*)d_out;

    // common small arrays
    float* wsf    = (float*)d_ws;                 // N
    int*   hist   = (int*)(wsf + N);              // N
    int*   startp = hist + N;                     // N+1
    int*   cursor = startp + N + 1;               // N (fallback only)
    uintptr_t aux_addr = ((uintptr_t)(cursor + N) + 15) & ~(uintptr_t)15;

    // choose chunk count B for the no-atomic path
    int Bn = 0; uintptr_t rec_addr = 0;
    if (N <= NMAX) {
        const int cands[3] = {256, 128, 64};
        for (int ci = 0; ci < 3; ci++) {
            int Bc = cands[ci];
            uintptr_t ra = aux_addr + (uintptr_t)2 * Bc * N * sizeof(uint32_t);
            ra = (ra + 15) & ~(uintptr_t)15;
            size_t need = (ra - (uintptr_t)d_ws) + (size_t)E * sizeof(uint32_t);
            if (need <= ws_size) { Bn = Bc; rec_addr = ra; break; }
        }
    }

    if (Bn > 0) {
        uint32_t* hist_b  = (uint32_t*)aux_addr;
        uint32_t* wsfix_b = hist_b + (size_t)Bn * N;
        uint32_t* rec     = (uint32_t*)rec_addr;
        int chunk = (E + Bn - 1) / Bn;
        // largest power-of-2 scale with chunk*scale < 2^32 (overflow-proof)
        int sh = 0;
        while (((uint64_t)chunk << (sh + 1)) < (1ull << 32)) sh++;
        float scale = (float)(1u << sh);
        double inv_scale = 1.0 / (double)(1u << sh);
        int nb16 = (N + 15) / 16;   // blocks of 16 nodes for reduce/offsets

        // no memset needed: every ws region below is fully overwritten before use
        k_pass1<<<Bn, 1024, 0, stream>>>(row, col, ew, hist_b, wsfix_b, E, chunk, N, scale);
        k_reduce2<<<nb16, 256, 0, stream>>>(hist_b, wsfix_b, hist, wsf, Bn, N, inv_scale);
        k_scan<<<1, SCANB, 0, stream>>>(hist, startp, (int*)nullptr, N);
        k_offsets2<<<nb16, 256, 0, stream>>>(hist_b, startp, Bn, N);
        k_build_chunk<<<Bn, 1024, 0, stream>>>(row, col, ew, wsf, hist_b, rec, E, chunk, N);
        k_gather<<<N, 64, 0, stream>>>(startp, rec, x, out, N);
    } else {
        // fallback: global-atomic CSC build
        uint32_t* rec = (uint32_t*)aux_addr;
        hipMemsetAsync(d_ws, 0, (size_t)2 * N * sizeof(int), stream);
        int eb = (E + 255) / 256;
        k_edge_pass1<<<eb, 256, 0, stream>>>(row, col, ew, wsf, hist, E);
        k_scan<<<1, SCANB, 0, stream>>>(hist, startp, cursor, N);
        k_build<<<eb, 256, 0, stream>>>(row, col, ew, wsf, cursor, rec, E);
        k_gather<<<N, 64, 0, stream>>>(startp, rec, x, out, N);
    }
}